// Round 1
// baseline (3553.766 us; speedup 1.0000x reference)
//
#include <hip/hip_runtime.h>
#include <hip/hip_bf16.h>
#include <cfloat>

// dims
#define N_B 32
#define QN 64
#define FN 16
#define LP 196
#define HN 12
#define DH 64
#define EE 768
#define KLEN 3136
#define CH 49   // chunk of patches per stage (196 = 4*49)

// ---------------------------------------------------------------------------
// C[m][n] = sum_k A[m][k] * W[n][k]    (A: [2048][768], W: [768][768])
// BM=128, BN=64, BK=16, 256 threads, 8x4 micro-tile
// ---------------------------------------------------------------------------
__global__ __launch_bounds__(256) void gemm_bt(const float* __restrict__ A,
                                               const float* __restrict__ W,
                                               float* __restrict__ C) {
    __shared__ float As[16][132];
    __shared__ float Bs[16][68];
    const int t  = threadIdx.x;
    const int m0 = blockIdx.x * 128;
    const int n0 = blockIdx.y * 64;
    const int ty = t >> 4, tx = t & 15;

    float acc[8][4];
#pragma unroll
    for (int r = 0; r < 8; ++r)
#pragma unroll
        for (int c = 0; c < 4; ++c) acc[r][c] = 0.f;

    for (int k0 = 0; k0 < EE; k0 += 16) {
        // stage A tile (128x16), transposed to k-major
#pragma unroll
        for (int u = 0; u < 2; ++u) {
            int idx = t + 256 * u;
            int row = idx >> 2, j4 = idx & 3;
            float4 av = *(const float4*)(A + (size_t)(m0 + row) * EE + k0 + j4 * 4);
            As[j4 * 4 + 0][row] = av.x;
            As[j4 * 4 + 1][row] = av.y;
            As[j4 * 4 + 2][row] = av.z;
            As[j4 * 4 + 3][row] = av.w;
        }
        // stage W tile (64x16), transposed to k-major
        {
            int row = t >> 2, j4 = t & 3;
            float4 wv = *(const float4*)(W + (size_t)(n0 + row) * EE + k0 + j4 * 4);
            Bs[j4 * 4 + 0][row] = wv.x;
            Bs[j4 * 4 + 1][row] = wv.y;
            Bs[j4 * 4 + 2][row] = wv.z;
            Bs[j4 * 4 + 3][row] = wv.w;
        }
        __syncthreads();
#pragma unroll
        for (int k = 0; k < 16; ++k) {
            float4 a0 = *(float4*)&As[k][ty * 8];
            float4 a1 = *(float4*)&As[k][ty * 8 + 4];
            float4 b0 = *(float4*)&Bs[k][tx * 4];
            float ar[8] = {a0.x, a0.y, a0.z, a0.w, a1.x, a1.y, a1.z, a1.w};
            float bc[4] = {b0.x, b0.y, b0.z, b0.w};
#pragma unroll
            for (int r = 0; r < 8; ++r)
#pragma unroll
                for (int c = 0; c < 4; ++c) acc[r][c] += ar[r] * bc[c];
        }
        __syncthreads();
    }
#pragma unroll
    for (int r = 0; r < 8; ++r) {
        float4 o = make_float4(acc[r][0], acc[r][1], acc[r][2], acc[r][3]);
        *(float4*)(C + (size_t)(m0 + ty * 8 + r) * EE + n0 + tx * 4) = o;
    }
}

// ---------------------------------------------------------------------------
// Attention: one block per (n,h). 256 threads: qq = t>>4 (4 queries each),
// pg = t&15 (patch-group in score phase / d-slice in mix phase).
// Per frame: 4 chunks of 49 patches, online (flash) softmax within frame.
// ---------------------------------------------------------------------------
__global__ __launch_bounds__(256, 2) void attn_fp32(const float* __restrict__ qs_g,
                                                    const float* __restrict__ k_g,
                                                    const float* __restrict__ v_g,
                                                    const int* __restrict__ m_g,
                                                    float* __restrict__ mix_g) {
    const int nb = blockIdx.x;
    const int n = nb / HN, h = nb % HN;

    __shared__ float qs_s[QN][68];
    __shared__ float K_s[CH][68];
    __shared__ float V_s[CH][68];
    __shared__ float P_s[CH][68];
    __shared__ int   msk_s[CH];

    const int t  = threadIdx.x;
    const int qq = t >> 4, pg = t & 15;

    // stage qs for this (n,h), pre-scaled by d^-0.5 = 0.125
#pragma unroll
    for (int u = 0; u < 4; ++u) {
        int idx = t + 256 * u;
        int qr = idx >> 4, c4 = idx & 15;
        float4 v = *(const float4*)(qs_g + ((size_t)n * QN + qr) * EE + h * DH + c4 * 4);
        v.x *= 0.125f; v.y *= 0.125f; v.z *= 0.125f; v.w *= 0.125f;
        *(float4*)&qs_s[qr][c4 * 4] = v;
    }
    __syncthreads();

    float mix[4][4];
#pragma unroll
    for (int r = 0; r < 4; ++r)
#pragma unroll
        for (int c = 0; c < 4; ++c) mix[r][c] = 0.f;

    for (int f = 0; f < FN; ++f) {
        float m_r[4], l_r[4], facc[4][4];
#pragma unroll
        for (int r = 0; r < 4; ++r) {
            m_r[r] = -FLT_MAX;
            l_r[r] = 0.f;
#pragma unroll
            for (int c = 0; c < 4; ++c) facc[r][c] = 0.f;
        }

        for (int cc = 0; cc < 4; ++cc) {
            const int kbase = f * LP + cc * CH;
            // stage K,V chunk (49 x 64 each) + mask
#pragma unroll
            for (int u = 0; u < 4; ++u) {
                int idx = t + 256 * u;
                if (idx < CH * 16) {
                    int p = idx >> 4, j4 = idx & 15;
                    size_t g = (((size_t)n * KLEN + kbase + p) * HN + h) * DH + j4 * 4;
                    *(float4*)&K_s[p][j4 * 4] = *(const float4*)(k_g + g);
                    *(float4*)&V_s[p][j4 * 4] = *(const float4*)(v_g + g);
                }
            }
            if (t < CH) msk_s[t] = m_g[(size_t)n * KLEN + kbase + t];
            __syncthreads();

            // block-uniform chunk-valid flag (mask is query-independent)
            bool valid = false;
            for (int pp = 0; pp < CH; ++pp) valid = valid || (msk_s[pp] != 0);
            if (!valid) continue;  // uniform skip: no P write, no mix, no syncs needed

            // ---- scores: s[r][i] = qs[q] . K[p],  p = pg + 16*i ----
            float s[4][4];
#pragma unroll
            for (int r = 0; r < 4; ++r)
#pragma unroll
                for (int i = 0; i < 4; ++i) s[r][i] = 0.f;

#pragma unroll
            for (int jc = 0; jc < 16; ++jc) {
                float4 a0 = *(float4*)&qs_s[qq * 4 + 0][jc * 4];
                float4 a1 = *(float4*)&qs_s[qq * 4 + 1][jc * 4];
                float4 a2 = *(float4*)&qs_s[qq * 4 + 2][jc * 4];
                float4 a3 = *(float4*)&qs_s[qq * 4 + 3][jc * 4];
#pragma unroll
                for (int i = 0; i < 3; ++i) {
                    float4 kv = *(float4*)&K_s[pg + 16 * i][jc * 4];
                    s[0][i] += a0.x * kv.x + a0.y * kv.y + a0.z * kv.z + a0.w * kv.w;
                    s[1][i] += a1.x * kv.x + a1.y * kv.y + a1.z * kv.z + a1.w * kv.w;
                    s[2][i] += a2.x * kv.x + a2.y * kv.y + a2.z * kv.z + a2.w * kv.w;
                    s[3][i] += a3.x * kv.x + a3.y * kv.y + a3.z * kv.z + a3.w * kv.w;
                }
                if (pg == 0) {  // patch 48 handled by pg==0 lanes only
                    float4 kv = *(float4*)&K_s[48][jc * 4];
                    s[0][3] += a0.x * kv.x + a0.y * kv.y + a0.z * kv.z + a0.w * kv.w;
                    s[1][3] += a1.x * kv.x + a1.y * kv.y + a1.z * kv.z + a1.w * kv.w;
                    s[2][3] += a2.x * kv.x + a2.y * kv.y + a2.z * kv.z + a2.w * kv.w;
                    s[3][3] += a3.x * kv.x + a3.y * kv.y + a3.z * kv.z + a3.w * kv.w;
                }
            }
            // apply mask (and invalidate the unused i=3 slot for pg!=0)
#pragma unroll
            for (int i = 0; i < 3; ++i) {
                if (!msk_s[pg + 16 * i]) {
                    s[0][i] = -FLT_MAX; s[1][i] = -FLT_MAX;
                    s[2][i] = -FLT_MAX; s[3][i] = -FLT_MAX;
                }
            }
            {
                bool p3ok = (pg == 0) && (msk_s[48] != 0);
                if (!p3ok) { s[0][3] = -FLT_MAX; s[1][3] = -FLT_MAX; s[2][3] = -FLT_MAX; s[3][3] = -FLT_MAX; }
            }

            // ---- online softmax update (per query r, across 16 pg lanes) ----
#pragma unroll
            for (int r = 0; r < 4; ++r) {
                float mx = fmaxf(fmaxf(s[r][0], s[r][1]), fmaxf(s[r][2], s[r][3]));
                mx = fmaxf(mx, __shfl_xor(mx, 1));
                mx = fmaxf(mx, __shfl_xor(mx, 2));
                mx = fmaxf(mx, __shfl_xor(mx, 4));
                mx = fmaxf(mx, __shfl_xor(mx, 8));
                float newm = fmaxf(m_r[r], mx);          // finite: chunk has >=1 valid
                float scale = __expf(m_r[r] - newm);     // 0 when m_r == -FLT_MAX
                float e0 = __expf(s[r][0] - newm);
                float e1 = __expf(s[r][1] - newm);
                float e2 = __expf(s[r][2] - newm);
                float e3 = __expf(s[r][3] - newm);
                float sum = e0 + e1 + e2 + e3;
                sum += __shfl_xor(sum, 1);
                sum += __shfl_xor(sum, 2);
                sum += __shfl_xor(sum, 4);
                sum += __shfl_xor(sum, 8);
#pragma unroll
                for (int c = 0; c < 4; ++c) facc[r][c] *= scale;
                l_r[r] = l_r[r] * scale + sum;
                m_r[r] = newm;
                s[r][0] = e0; s[r][1] = e1; s[r][2] = e2; s[r][3] = e3;
            }

            // ---- write P transposed: P_s[p][q] ----
#pragma unroll
            for (int i = 0; i < 3; ++i) {
                float4 pv = make_float4(s[0][i], s[1][i], s[2][i], s[3][i]);
                *(float4*)&P_s[pg + 16 * i][qq * 4] = pv;
            }
            if (pg == 0) {
                float4 pv = make_float4(s[0][3], s[1][3], s[2][3], s[3][3]);
                *(float4*)&P_s[48][qq * 4] = pv;
            }
            __syncthreads();

            // ---- mix: facc[r][c] += sum_p P[p][q] * V[p][d],  d = pg*4+c ----
            for (int p = 0; p < CH; ++p) {
                float4 pv = *(float4*)&P_s[p][qq * 4];
                float4 vv = *(float4*)&V_s[p][pg * 4];
                facc[0][0] += pv.x * vv.x; facc[0][1] += pv.x * vv.y;
                facc[0][2] += pv.x * vv.z; facc[0][3] += pv.x * vv.w;
                facc[1][0] += pv.y * vv.x; facc[1][1] += pv.y * vv.y;
                facc[1][2] += pv.y * vv.z; facc[1][3] += pv.y * vv.w;
                facc[2][0] += pv.z * vv.x; facc[2][1] += pv.z * vv.y;
                facc[2][2] += pv.z * vv.z; facc[2][3] += pv.z * vv.w;
                facc[3][0] += pv.w * vv.x; facc[3][1] += pv.w * vv.y;
                facc[3][2] += pv.w * vv.z; facc[3][3] += pv.w * vv.w;
            }
            __syncthreads();
        }

        // frame finalize: mix += facc / l
#pragma unroll
        for (int r = 0; r < 4; ++r) {
            float inv = 1.0f / l_r[r];   // l > 0: >=1 valid patch per frame guaranteed
#pragma unroll
            for (int c = 0; c < 4; ++c) mix[r][c] += facc[r][c] * inv;
        }
    }

    // store mix[q][d] into [n][q][h*64+d]
#pragma unroll
    for (int r = 0; r < 4; ++r) {
        float4 o = make_float4(mix[r][0], mix[r][1], mix[r][2], mix[r][3]);
        *(float4*)(mix_g + ((size_t)n * QN + qq * 4 + r) * EE + h * DH + pg * 4) = o;
    }
}

// ---------------------------------------------------------------------------
extern "C" void kernel_launch(void* const* d_in, const int* in_sizes, int n_in,
                              void* d_out, int out_size, void* d_ws, size_t ws_size,
                              hipStream_t stream) {
    const float* q  = (const float*)d_in[0];
    const float* k  = (const float*)d_in[1];
    const float* v  = (const float*)d_in[2];
    const int*   m  = (const int*)d_in[3];
    const float* Wi = (const float*)d_in[4];
    const float* Wo = (const float*)d_in[5];

    float* out = (float*)d_out;
    float* qs  = out + (size_t)N_B * QN * EE;  // second output region (qs_out), also attn input
    float* mix = (float*)d_ws;                 // 2048*768 fp32 scratch

    dim3 ggrid(2048 / 128, EE / 64);
    gemm_bt<<<ggrid, 256, 0, stream>>>(q, Wi, qs);                       // in-proj
    attn_fp32<<<dim3(N_B * HN), 256, 0, stream>>>(qs, k, v, m, mix);     // attention
    gemm_bt<<<ggrid, 256, 0, stream>>>(mix, Wo, out);                    // out-proj
}

// Round 2
// 3304.326 us; speedup vs baseline: 1.0755x; 1.0755x over previous
//
#include <hip/hip_runtime.h>
#include <hip/hip_bf16.h>
#include <cfloat>

// dims
#define N_B 32
#define QN 64
#define FN 16
#define LP 196
#define HN 12
#define DH 64
#define EE 768
#define KLEN 3136
#define CH 49   // chunk of patches per stage (196 = 4*49)

// ---------------------------------------------------------------------------
// C[m][n] = sum_k A[m][k] * W[n][k]    (A: [2048][768], W: [768][768])
// BM=128, BN=64, BK=16, 256 threads, 8x4 micro-tile
// ---------------------------------------------------------------------------
__global__ __launch_bounds__(256) void gemm_bt(const float* __restrict__ A,
                                               const float* __restrict__ W,
                                               float* __restrict__ C) {
    __shared__ float As[16][132];
    __shared__ float Bs[16][68];
    const int t  = threadIdx.x;
    const int m0 = blockIdx.x * 128;
    const int n0 = blockIdx.y * 64;
    const int ty = t >> 4, tx = t & 15;

    float acc[8][4];
#pragma unroll
    for (int r = 0; r < 8; ++r)
#pragma unroll
        for (int c = 0; c < 4; ++c) acc[r][c] = 0.f;

    for (int k0 = 0; k0 < EE; k0 += 16) {
#pragma unroll
        for (int u = 0; u < 2; ++u) {
            int idx = t + 256 * u;
            int row = idx >> 2, j4 = idx & 3;
            float4 av = *(const float4*)(A + (size_t)(m0 + row) * EE + k0 + j4 * 4);
            As[j4 * 4 + 0][row] = av.x;
            As[j4 * 4 + 1][row] = av.y;
            As[j4 * 4 + 2][row] = av.z;
            As[j4 * 4 + 3][row] = av.w;
        }
        {
            int row = t >> 2, j4 = t & 3;
            float4 wv = *(const float4*)(W + (size_t)(n0 + row) * EE + k0 + j4 * 4);
            Bs[j4 * 4 + 0][row] = wv.x;
            Bs[j4 * 4 + 1][row] = wv.y;
            Bs[j4 * 4 + 2][row] = wv.z;
            Bs[j4 * 4 + 3][row] = wv.w;
        }
        __syncthreads();
#pragma unroll
        for (int k = 0; k < 16; ++k) {
            float4 a0 = *(float4*)&As[k][ty * 8];
            float4 a1 = *(float4*)&As[k][ty * 8 + 4];
            float4 b0 = *(float4*)&Bs[k][tx * 4];
            float ar[8] = {a0.x, a0.y, a0.z, a0.w, a1.x, a1.y, a1.z, a1.w};
            float bc[4] = {b0.x, b0.y, b0.z, b0.w};
#pragma unroll
            for (int r = 0; r < 8; ++r)
#pragma unroll
                for (int c = 0; c < 4; ++c) acc[r][c] += ar[r] * bc[c];
        }
        __syncthreads();
    }
#pragma unroll
    for (int r = 0; r < 8; ++r) {
        float4 o = make_float4(acc[r][0], acc[r][1], acc[r][2], acc[r][3]);
        *(float4*)(C + (size_t)(m0 + ty * 8 + r) * EE + n0 + tx * 4) = o;
    }
}

__global__ __launch_bounds__(256) void zero_f32(float* __restrict__ p, int n4) {
    int i = blockIdx.x * 256 + threadIdx.x;
    if (i < n4) ((float4*)p)[i] = make_float4(0.f, 0.f, 0.f, 0.f);
}

// ---------------------------------------------------------------------------
// Attention, one block per (n, h, frame). 256 threads: qq=t>>4 (4 queries),
// pg=t&15. 4 chunks of 49 patches per frame, online softmax within frame,
// register-prefetch double buffering of the K/V chunk staging.
// Frame contribution facc/l is atomically accumulated into mix.
// ---------------------------------------------------------------------------
__global__ __launch_bounds__(256, 2) void attn_frame(const float* __restrict__ qs_g,
                                                     const float* __restrict__ k_g,
                                                     const float* __restrict__ v_g,
                                                     const int* __restrict__ m_g,
                                                     float* __restrict__ mix_g) {
    const int nh = blockIdx.x;
    const int f  = blockIdx.y;
    const int n = nh / HN, h = nh % HN;

    __shared__ float qs_s[QN][68];
    __shared__ float K_s[CH][68];
    __shared__ float V_s[CH][68];
    __shared__ float P_s[CH][68];
    __shared__ int   msk_s[CH];

    const int t  = threadIdx.x;
    const int qq = t >> 4, pg = t & 15;

    // stage qs for this (n,h), pre-scaled by d^-0.5 = 0.125
#pragma unroll
    for (int u = 0; u < 4; ++u) {
        int idx = t + 256 * u;
        int qr = idx >> 4, c4 = idx & 15;
        float4 v = *(const float4*)(qs_g + ((size_t)n * QN + qr) * EE + h * DH + c4 * 4);
        v.x *= 0.125f; v.y *= 0.125f; v.z *= 0.125f; v.w *= 0.125f;
        *(float4*)&qs_s[qr][c4 * 4] = v;
    }

    // register prefetch buffers for K/V chunk staging
    float4 kr[4], vr[4];
    int mr;
#define PREFETCH(cc_)                                                              \
    do {                                                                           \
        const int kbase_ = f * LP + (cc_) * CH;                                    \
        _Pragma("unroll")                                                          \
        for (int u = 0; u < 4; ++u) {                                              \
            int idx = t + 256 * u;                                                 \
            if (idx < CH * 16) {                                                   \
                int p = idx >> 4, j4 = idx & 15;                                   \
                size_t g = (((size_t)n * KLEN + kbase_ + p) * HN + h) * DH + j4*4; \
                kr[u] = *(const float4*)(k_g + g);                                 \
                vr[u] = *(const float4*)(v_g + g);                                 \
            }                                                                      \
        }                                                                          \
        mr = (t < CH) ? m_g[(size_t)n * KLEN + kbase_ + t] : 0;                    \
    } while (0)

    PREFETCH(0);

    float m_r[4], l_r[4], facc[4][4];
#pragma unroll
    for (int r = 0; r < 4; ++r) {
        m_r[r] = -FLT_MAX;
        l_r[r] = 0.f;
#pragma unroll
        for (int c = 0; c < 4; ++c) facc[r][c] = 0.f;
    }

    for (int cc = 0; cc < 4; ++cc) {
        // write staged registers to LDS
#pragma unroll
        for (int u = 0; u < 4; ++u) {
            int idx = t + 256 * u;
            if (idx < CH * 16) {
                int p = idx >> 4, j4 = idx & 15;
                *(float4*)&K_s[p][j4 * 4] = kr[u];
                *(float4*)&V_s[p][j4 * 4] = vr[u];
            }
        }
        if (t < CH) msk_s[t] = mr;
        int anyvalid = __syncthreads_or(mr != 0);  // also covers qs_s/LDS staging

        if (cc < 3) PREFETCH(cc + 1);  // overlap next chunk's HBM latency with compute

        if (anyvalid) {
            // ---- scores: s[r][i] = qs[q] . K[p],  p = pg + 16*i ----
            float s[4][4];
#pragma unroll
            for (int r = 0; r < 4; ++r)
#pragma unroll
                for (int i = 0; i < 4; ++i) s[r][i] = 0.f;

#pragma unroll
            for (int jc = 0; jc < 16; ++jc) {
                float4 a0 = *(float4*)&qs_s[qq * 4 + 0][jc * 4];
                float4 a1 = *(float4*)&qs_s[qq * 4 + 1][jc * 4];
                float4 a2 = *(float4*)&qs_s[qq * 4 + 2][jc * 4];
                float4 a3 = *(float4*)&qs_s[qq * 4 + 3][jc * 4];
#pragma unroll
                for (int i = 0; i < 3; ++i) {
                    float4 kv = *(float4*)&K_s[pg + 16 * i][jc * 4];
                    s[0][i] += a0.x * kv.x + a0.y * kv.y + a0.z * kv.z + a0.w * kv.w;
                    s[1][i] += a1.x * kv.x + a1.y * kv.y + a1.z * kv.z + a1.w * kv.w;
                    s[2][i] += a2.x * kv.x + a2.y * kv.y + a2.z * kv.z + a2.w * kv.w;
                    s[3][i] += a3.x * kv.x + a3.y * kv.y + a3.z * kv.z + a3.w * kv.w;
                }
                if (pg == 0) {
                    float4 kv = *(float4*)&K_s[48][jc * 4];
                    s[0][3] += a0.x * kv.x + a0.y * kv.y + a0.z * kv.z + a0.w * kv.w;
                    s[1][3] += a1.x * kv.x + a1.y * kv.y + a1.z * kv.z + a1.w * kv.w;
                    s[2][3] += a2.x * kv.x + a2.y * kv.y + a2.z * kv.z + a2.w * kv.w;
                    s[3][3] += a3.x * kv.x + a3.y * kv.y + a3.z * kv.z + a3.w * kv.w;
                }
            }
#pragma unroll
            for (int i = 0; i < 3; ++i) {
                if (!msk_s[pg + 16 * i]) {
                    s[0][i] = -FLT_MAX; s[1][i] = -FLT_MAX;
                    s[2][i] = -FLT_MAX; s[3][i] = -FLT_MAX;
                }
            }
            {
                bool p3ok = (pg == 0) && (msk_s[48] != 0);
                if (!p3ok) { s[0][3] = -FLT_MAX; s[1][3] = -FLT_MAX; s[2][3] = -FLT_MAX; s[3][3] = -FLT_MAX; }
            }

            // ---- online softmax update (per query r, across 16 pg lanes) ----
#pragma unroll
            for (int r = 0; r < 4; ++r) {
                float mx = fmaxf(fmaxf(s[r][0], s[r][1]), fmaxf(s[r][2], s[r][3]));
                mx = fmaxf(mx, __shfl_xor(mx, 1));
                mx = fmaxf(mx, __shfl_xor(mx, 2));
                mx = fmaxf(mx, __shfl_xor(mx, 4));
                mx = fmaxf(mx, __shfl_xor(mx, 8));
                float newm = fmaxf(m_r[r], mx);
                float scale = __expf(m_r[r] - newm);
                float e0 = __expf(s[r][0] - newm);
                float e1 = __expf(s[r][1] - newm);
                float e2 = __expf(s[r][2] - newm);
                float e3 = __expf(s[r][3] - newm);
                float sum = e0 + e1 + e2 + e3;
                sum += __shfl_xor(sum, 1);
                sum += __shfl_xor(sum, 2);
                sum += __shfl_xor(sum, 4);
                sum += __shfl_xor(sum, 8);
#pragma unroll
                for (int c = 0; c < 4; ++c) facc[r][c] *= scale;
                l_r[r] = l_r[r] * scale + sum;
                m_r[r] = newm;
                s[r][0] = e0; s[r][1] = e1; s[r][2] = e2; s[r][3] = e3;
            }

            // ---- write P transposed: P_s[p][q] ----
#pragma unroll
            for (int i = 0; i < 3; ++i) {
                float4 pv = make_float4(s[0][i], s[1][i], s[2][i], s[3][i]);
                *(float4*)&P_s[pg + 16 * i][qq * 4] = pv;
            }
            if (pg == 0) {
                float4 pv = make_float4(s[0][3], s[1][3], s[2][3], s[3][3]);
                *(float4*)&P_s[48][qq * 4] = pv;
            }
            __syncthreads();

            // ---- mix: facc[r][c] += sum_p P[p][q] * V[p][d],  d = pg*4+c ----
            for (int p = 0; p < CH; ++p) {
                float4 pv = *(float4*)&P_s[p][qq * 4];
                float4 vv = *(float4*)&V_s[p][pg * 4];
                facc[0][0] += pv.x * vv.x; facc[0][1] += pv.x * vv.y;
                facc[0][2] += pv.x * vv.z; facc[0][3] += pv.x * vv.w;
                facc[1][0] += pv.y * vv.x; facc[1][1] += pv.y * vv.y;
                facc[1][2] += pv.y * vv.z; facc[1][3] += pv.y * vv.w;
                facc[2][0] += pv.z * vv.x; facc[2][1] += pv.z * vv.y;
                facc[2][2] += pv.z * vv.z; facc[2][3] += pv.z * vv.w;
                facc[3][0] += pv.w * vv.x; facc[3][1] += pv.w * vv.y;
                facc[3][2] += pv.w * vv.z; facc[3][3] += pv.w * vv.w;
            }
        }
        __syncthreads();  // protect K_s/V_s/P_s overwrite next iteration
    }
#undef PREFETCH

    // frame contribution -> atomic accumulate into mix[n][q][h*64+d]
#pragma unroll
    for (int r = 0; r < 4; ++r) {
        float inv = 1.0f / l_r[r];  // l>0: >=1 valid patch per frame guaranteed
        float* dst = mix_g + ((size_t)n * QN + qq * 4 + r) * EE + h * DH + pg * 4;
#pragma unroll
        for (int c = 0; c < 4; ++c) atomicAdd(dst + c, facc[r][c] * inv);
    }
}

// ---------------------------------------------------------------------------
extern "C" void kernel_launch(void* const* d_in, const int* in_sizes, int n_in,
                              void* d_out, int out_size, void* d_ws, size_t ws_size,
                              hipStream_t stream) {
    const float* q  = (const float*)d_in[0];
    const float* k  = (const float*)d_in[1];
    const float* v  = (const float*)d_in[2];
    const int*   m  = (const int*)d_in[3];
    const float* Wi = (const float*)d_in[4];
    const float* Wo = (const float*)d_in[5];

    float* out = (float*)d_out;
    float* qs  = out + (size_t)N_B * QN * EE;  // second output region (qs_out), also attn input
    float* mix = (float*)d_ws;                 // 2048*768 fp32 scratch (accumulated via atomics)

    const int mix_n4 = (N_B * QN * EE) / 4;
    dim3 ggrid(2048 / 128, EE / 64);
    gemm_bt<<<ggrid, 256, 0, stream>>>(q, Wi, qs);                           // in-proj
    zero_f32<<<(mix_n4 + 255) / 256, 256, 0, stream>>>(mix, mix_n4);         // zero mix
    attn_frame<<<dim3(N_B * HN, FN), 256, 0, stream>>>(qs, k, v, m, mix);    // attention
    gemm_bt<<<ggrid, 256, 0, stream>>>(mix, Wo, out);                        // out-proj
}

// Round 3
// 309.587 us; speedup vs baseline: 11.4791x; 10.6733x over previous
//
#include <hip/hip_runtime.h>
#include <hip/hip_bf16.h>
#include <cfloat>

// dims
#define N_B 32
#define QN 64
#define FN 16
#define LP 196
#define HN 12
#define DH 64
#define EE 768
#define KLEN 3136
#define FPB 4          // frames per block
#define KROWS 208      // padded patches per frame for QK (13*16)
#define KST 72         // K_s / Q_s row stride in bf16 (144B: 2-way banks, 16B-aligned)
#define VST 232        // Vt_s / Pt_s row stride in bf16 (464B: 2-way banks, 16B-aligned)
#define PCOLS 224      // padded patches for PV k-dim (7*32)

typedef short s16x4 __attribute__((ext_vector_type(4)));
typedef __bf16 bf16x8 __attribute__((ext_vector_type(8)));
typedef float f32x4 __attribute__((ext_vector_type(4)));

__device__ __forceinline__ unsigned short f2bf(float x) {  // RNE fp32->bf16 bits
    unsigned u = __builtin_bit_cast(unsigned, x);
    u += 0x7fffu + ((u >> 16) & 1u);
    return (unsigned short)(u >> 16);
}

// ---------------------------------------------------------------------------
// C[m][n] = sum_k A[m][k] * W[n][k]   (A: [2048][768], W: [768][768]) fp32
// ---------------------------------------------------------------------------
__global__ __launch_bounds__(256) void gemm_bt(const float* __restrict__ A,
                                               const float* __restrict__ W,
                                               float* __restrict__ C) {
    __shared__ float As[16][132];
    __shared__ float Bs[16][68];
    const int t  = threadIdx.x;
    const int m0 = blockIdx.x * 128;
    const int n0 = blockIdx.y * 64;
    const int ty = t >> 4, tx = t & 15;

    float acc[8][4];
#pragma unroll
    for (int r = 0; r < 8; ++r)
#pragma unroll
        for (int c = 0; c < 4; ++c) acc[r][c] = 0.f;

    for (int k0 = 0; k0 < EE; k0 += 16) {
#pragma unroll
        for (int u = 0; u < 2; ++u) {
            int idx = t + 256 * u;
            int row = idx >> 2, j4 = idx & 3;
            float4 av = *(const float4*)(A + (size_t)(m0 + row) * EE + k0 + j4 * 4);
            As[j4 * 4 + 0][row] = av.x;
            As[j4 * 4 + 1][row] = av.y;
            As[j4 * 4 + 2][row] = av.z;
            As[j4 * 4 + 3][row] = av.w;
        }
        {
            int row = t >> 2, j4 = t & 3;
            float4 wv = *(const float4*)(W + (size_t)(n0 + row) * EE + k0 + j4 * 4);
            Bs[j4 * 4 + 0][row] = wv.x;
            Bs[j4 * 4 + 1][row] = wv.y;
            Bs[j4 * 4 + 2][row] = wv.z;
            Bs[j4 * 4 + 3][row] = wv.w;
        }
        __syncthreads();
#pragma unroll
        for (int k = 0; k < 16; ++k) {
            float4 a0 = *(float4*)&As[k][ty * 8];
            float4 a1 = *(float4*)&As[k][ty * 8 + 4];
            float4 b0 = *(float4*)&Bs[k][tx * 4];
            float ar[8] = {a0.x, a0.y, a0.z, a0.w, a1.x, a1.y, a1.z, a1.w};
            float bc[4] = {b0.x, b0.y, b0.z, b0.w};
#pragma unroll
            for (int r = 0; r < 8; ++r)
#pragma unroll
                for (int c = 0; c < 4; ++c) acc[r][c] += ar[r] * bc[c];
        }
        __syncthreads();
    }
#pragma unroll
    for (int r = 0; r < 8; ++r) {
        float4 o = make_float4(acc[r][0], acc[r][1], acc[r][2], acc[r][3]);
        *(float4*)(C + (size_t)(m0 + ty * 8 + r) * EE + n0 + tx * 4) = o;
    }
}

__global__ __launch_bounds__(256) void zero_f32(float* __restrict__ p, int n4) {
    int i = blockIdx.x * 256 + threadIdx.x;
    if (i < n4) ((float4*)p)[i] = make_float4(0.f, 0.f, 0.f, 0.f);
}

// ---------------------------------------------------------------------------
// MFMA attention. Block = (h, frame-group, n); 4 waves; wave w owns queries
// [w*16, w*16+16). Per frame: stage K(bf16) -> QK^T via mfma(K,Q) (scores in
// regs, col=q) -> register softmax -> Pt/Vt to LDS -> PV via mfma(Pt,Vt).
// Frame result * (1/l) accumulated; atomicAdd into mix at the end.
// ---------------------------------------------------------------------------
__global__ __launch_bounds__(256, 2) void attn_mfma(const float* __restrict__ qs_g,
                                                    const float* __restrict__ k_g,
                                                    const float* __restrict__ v_g,
                                                    const int* __restrict__ m_g,
                                                    float* __restrict__ mix_g) {
    const int h = blockIdx.x, fg = blockIdx.y, n = blockIdx.z;

    __shared__ unsigned short KV_s[KROWS * KST];  // K view: [208][72]; Vt view: [64][232]
    __shared__ unsigned short Pt_s[64 * VST];     // P^T: [q=64][p=224]
    __shared__ unsigned short Q_s[64 * KST];      // Q:   [q=64][d=64]
    __shared__ float bias_s[224];
    __shared__ float linv_s[4][16];

    const int t = threadIdx.x;
    const int w = t >> 6, lane = t & 63, lr = lane & 15, lg = lane >> 4;

    // zero Pt pad cols [208,224) once (PV reads them; V pad cols are zeroed too,
    // but garbage*0 could be NaN if garbage were Inf/NaN)
    {
        int qr = t >> 2, c0 = 208 + (t & 3) * 4;
        *(s16x4*)&Pt_s[qr * VST + c0] = (s16x4){0, 0, 0, 0};
    }
    // stage Q (scaled by d^-0.5), fp32 -> bf16
#pragma unroll
    for (int u = 0; u < 4; ++u) {
        int idx = t + 256 * u;
        int qr = idx >> 4, j4 = idx & 15;
        f32x4 v = *(const f32x4*)(qs_g + ((size_t)n * QN + qr) * EE + h * DH + j4 * 4);
        s16x4 b = {(short)f2bf(v[0] * 0.125f), (short)f2bf(v[1] * 0.125f),
                   (short)f2bf(v[2] * 0.125f), (short)f2bf(v[3] * 0.125f)};
        *(s16x4*)&Q_s[qr * KST + j4 * 4] = b;
    }

    float mix[4][4];
#pragma unroll
    for (int dt = 0; dt < 4; ++dt)
#pragma unroll
        for (int r = 0; r < 4; ++r) mix[dt][r] = 0.f;

    for (int ff = 0; ff < FPB; ++ff) {
        const int f = fg * FPB + ff;
        const size_t kbase = (size_t)n * KLEN + f * LP;

        __syncthreads();  // previous PV / bias readers done before overwrite

        // ---- stage K rows [0,208) (zeros beyond 196), fp32 -> bf16 ----
#pragma unroll
        for (int u = 0; u < 13; ++u) {
            int idx = t + 256 * u;
            int p = idx >> 4, j4 = idx & 15;
            s16x4 b = {0, 0, 0, 0};
            if (p < LP) {
                f32x4 kv = *(const f32x4*)(k_g + ((kbase + p) * HN + h) * DH + j4 * 4);
                b = (s16x4){(short)f2bf(kv[0]), (short)f2bf(kv[1]),
                            (short)f2bf(kv[2]), (short)f2bf(kv[3])};
            }
            *(s16x4*)&KV_s[p * KST + j4 * 4] = b;
        }
        if (t < 224) {
            float bv = -1e30f;
            if (t < LP && m_g[kbase + t] != 0) bv = 0.f;
            bias_s[t] = bv;
        }
        __syncthreads();

        // ---- QK^T: sc[tile] layout col=q(lr), row=p(lg*4+reg) ----
        bf16x8 qb0 = *(const bf16x8*)&Q_s[(w * 16 + lr) * KST + lg * 8];
        bf16x8 qb1 = *(const bf16x8*)&Q_s[(w * 16 + lr) * KST + 32 + lg * 8];
        f32x4 sc[13];
#pragma unroll
        for (int tl = 0; tl < 13; ++tl) {
            bf16x8 a0 = *(const bf16x8*)&KV_s[(tl * 16 + lr) * KST + lg * 8];
            bf16x8 a1 = *(const bf16x8*)&KV_s[(tl * 16 + lr) * KST + 32 + lg * 8];
            f32x4 z = {0.f, 0.f, 0.f, 0.f};
            z = __builtin_amdgcn_mfma_f32_16x16x32_bf16(a0, qb0, z, 0, 0, 0);
            sc[tl] = __builtin_amdgcn_mfma_f32_16x16x32_bf16(a1, qb1, z, 0, 0, 0);
        }

        // ---- issue V loads early (latency hides under softmax) ----
        f32x4 vr0[7], vr1[7];
#pragma unroll
        for (int u = 0; u < 7; ++u) {
            int unit = t + 256 * u;
            int pp = unit >> 4, d4 = unit & 15;
            int p0 = pp * 2;
            vr0[u] = (f32x4){0.f, 0.f, 0.f, 0.f};
            vr1[u] = (f32x4){0.f, 0.f, 0.f, 0.f};
            if (p0 < LP) {
                const float* vg = v_g + ((kbase + p0) * HN + h) * DH + d4 * 4;
                vr0[u] = *(const f32x4*)vg;
                vr1[u] = *(const f32x4*)(vg + (size_t)HN * DH);
            }
        }

        // ---- register softmax over 208 patches (52 regs + xor16/xor32) ----
        float mx = -FLT_MAX;
#pragma unroll
        for (int tl = 0; tl < 13; ++tl)
#pragma unroll
            for (int r = 0; r < 4; ++r) {
                float sv = sc[tl][r] + bias_s[tl * 16 + lg * 4 + r];
                sc[tl][r] = sv;
                mx = fmaxf(mx, sv);
            }
        mx = fmaxf(mx, __shfl_xor(mx, 16));
        mx = fmaxf(mx, __shfl_xor(mx, 32));
        float sum = 0.f;
#pragma unroll
        for (int tl = 0; tl < 13; ++tl)
#pragma unroll
            for (int r = 0; r < 4; ++r) {
                float e = __expf(sc[tl][r] - mx);
                sc[tl][r] = e;
                sum += e;
            }
        sum += __shfl_xor(sum, 16);
        sum += __shfl_xor(sum, 32);
        if (lane < 16) linv_s[w][lane] = 1.0f / sum;

        // ---- write P^T (wave-private rows): 4 consecutive patches per b64 ----
#pragma unroll
        for (int tl = 0; tl < 13; ++tl) {
            s16x4 pb = {(short)f2bf(sc[tl][0]), (short)f2bf(sc[tl][1]),
                        (short)f2bf(sc[tl][2]), (short)f2bf(sc[tl][3])};
            *(s16x4*)&Pt_s[(w * 16 + lr) * VST + tl * 16 + lg * 4] = pb;
        }
        __syncthreads();  // all waves done reading K before Vt overwrites union

        // ---- write V^T into union buffer: pair-packed b32 stores ----
#pragma unroll
        for (int u = 0; u < 7; ++u) {
            int unit = t + 256 * u;
            int pp = unit >> 4, d4 = (unit & 15) * 4;
            int p0 = pp * 2;
#pragma unroll
            for (int i = 0; i < 4; ++i) {
                unsigned pk = (unsigned)f2bf(vr0[u][i]) | ((unsigned)f2bf(vr1[u][i]) << 16);
                *(unsigned*)&KV_s[(d4 + i) * VST + p0] = pk;
            }
        }
        __syncthreads();

        // ---- PV: C[q][d] = sum_p Pt[q][p] * Vt[d][p] ----
        f32x4 pv[4];
#pragma unroll
        for (int dt = 0; dt < 4; ++dt) pv[dt] = (f32x4){0.f, 0.f, 0.f, 0.f};
#pragma unroll
        for (int ks = 0; ks < 7; ++ks) {
            bf16x8 a = *(const bf16x8*)&Pt_s[(w * 16 + lr) * VST + ks * 32 + lg * 8];
#pragma unroll
            for (int dt = 0; dt < 4; ++dt) {
                bf16x8 b = *(const bf16x8*)&KV_s[(dt * 16 + lr) * VST + ks * 32 + lg * 8];
                pv[dt] = __builtin_amdgcn_mfma_f32_16x16x32_bf16(a, b, pv[dt], 0, 0, 0);
            }
        }
        float li[4];
#pragma unroll
        for (int r = 0; r < 4; ++r) li[r] = linv_s[w][lg * 4 + r];
#pragma unroll
        for (int dt = 0; dt < 4; ++dt)
#pragma unroll
            for (int r = 0; r < 4; ++r) mix[dt][r] += pv[dt][r] * li[r];
    }

    // ---- accumulate into mix[n][q][h*64+d] ----
#pragma unroll
    for (int dt = 0; dt < 4; ++dt)
#pragma unroll
        for (int r = 0; r < 4; ++r)
            atomicAdd(mix_g + ((size_t)n * QN + w * 16 + lg * 4 + r) * EE + h * DH + dt * 16 + lr,
                      mix[dt][r]);
}

// ---------------------------------------------------------------------------
extern "C" void kernel_launch(void* const* d_in, const int* in_sizes, int n_in,
                              void* d_out, int out_size, void* d_ws, size_t ws_size,
                              hipStream_t stream) {
    const float* q  = (const float*)d_in[0];
    const float* k  = (const float*)d_in[1];
    const float* v  = (const float*)d_in[2];
    const int*   m  = (const int*)d_in[3];
    const float* Wi = (const float*)d_in[4];
    const float* Wo = (const float*)d_in[5];

    float* out = (float*)d_out;
    float* qs  = out + (size_t)N_B * QN * EE;  // second output (qs_out), also attn input
    float* mix = (float*)d_ws;                 // 2048x768 fp32 scratch (atomic-accumulated)

    const int mix_n4 = (N_B * QN * EE) / 4;
    dim3 ggrid(2048 / 128, EE / 64);
    gemm_bt<<<ggrid, 256, 0, stream>>>(q, Wi, qs);                               // in-proj
    zero_f32<<<(mix_n4 + 255) / 256, 256, 0, stream>>>(mix, mix_n4);             // zero mix
    attn_mfma<<<dim3(HN, FN / FPB, N_B), 256, 0, stream>>>(qs, k, v, m, mix);    // attention
    gemm_bt<<<ggrid, 256, 0, stream>>>(mix, Wo, out);                            // out-proj
}

// Round 4
// 236.784 us; speedup vs baseline: 15.0085x; 1.3075x over previous
//
#include <hip/hip_runtime.h>
#include <hip/hip_bf16.h>
#include <cfloat>

// dims
#define N_B 32
#define QN 64
#define FN 16
#define LP 196
#define HN 12
#define DH 64
#define EE 768
#define KLEN 3136
#define FPB 4          // frames per block (attn)
#define KROWS 208      // padded patches per frame for QK (13*16)
#define VST 232        // Vt_s / Pt_s row stride in bf16 (464B = 29*16B)

typedef short s16x4 __attribute__((ext_vector_type(4)));
typedef __bf16 bf16x8 __attribute__((ext_vector_type(8)));
typedef float f32x4 __attribute__((ext_vector_type(4)));

__device__ __forceinline__ bf16x8 cvt8(f32x4 a, f32x4 b) {
    bf16x8 r;
    r[0] = (__bf16)a[0]; r[1] = (__bf16)a[1]; r[2] = (__bf16)a[2]; r[3] = (__bf16)a[3];
    r[4] = (__bf16)b[0]; r[5] = (__bf16)b[1]; r[6] = (__bf16)b[2]; r[7] = (__bf16)b[3];
    return r;
}
__device__ __forceinline__ unsigned short bfb(float x) {
    return __builtin_bit_cast(unsigned short, (__bf16)x);
}

// ---------------------------------------------------------------------------
// bf16 MFMA GEMM: C[m][n] = sum_k A[m][k] * W[n][k]  (fp32 in, fp32 out)
// BM=64, BN=48, BK=32; 256 threads = 4 waves; wave w owns rows w*16..+16.
// ---------------------------------------------------------------------------
__global__ __launch_bounds__(256) void gemm_mfma(const float* __restrict__ A,
                                                 const float* __restrict__ W,
                                                 float* __restrict__ C) {
    __shared__ unsigned short As[64 * 72];
    __shared__ unsigned short Ws[48 * 72];
    const int t = threadIdx.x;
    const int w = t >> 6, lane = t & 63, lr = lane & 15, lg = lane >> 4;
    const int m0 = blockIdx.x * 64;
    const int n0 = blockIdx.y * 48;

    f32x4 acc[3];
#pragma unroll
    for (int ct = 0; ct < 3; ++ct) acc[ct] = (f32x4){0.f, 0.f, 0.f, 0.f};

    for (int k0 = 0; k0 < EE; k0 += 32) {
        // stage A 64x32: 1 unit/thread (16B bf16 write)
        {
            int row = t >> 2, cb = t & 3;
            const float* src = A + (size_t)(m0 + row) * EE + k0 + cb * 8;
            f32x4 a = *(const f32x4*)src, b = *(const f32x4*)(src + 4);
            *(bf16x8*)&As[row * 72 + cb * 8] = cvt8(a, b);
        }
        // stage W 48x32
        if (t < 192) {
            int row = t >> 2, cb = t & 3;
            const float* src = W + (size_t)(n0 + row) * EE + k0 + cb * 8;
            f32x4 a = *(const f32x4*)src, b = *(const f32x4*)(src + 4);
            *(bf16x8*)&Ws[row * 72 + cb * 8] = cvt8(a, b);
        }
        __syncthreads();
        bf16x8 a = *(const bf16x8*)&As[(w * 16 + lr) * 72 + lg * 8];
#pragma unroll
        for (int ct = 0; ct < 3; ++ct) {
            bf16x8 b = *(const bf16x8*)&Ws[(ct * 16 + lr) * 72 + lg * 8];
            acc[ct] = __builtin_amdgcn_mfma_f32_16x16x32_bf16(a, b, acc[ct], 0, 0, 0);
        }
        __syncthreads();
    }
    // C[m0 + w*16 + lg*4 + r][n0 + ct*16 + lr]
#pragma unroll
    for (int ct = 0; ct < 3; ++ct)
#pragma unroll
        for (int r = 0; r < 4; ++r)
            C[(size_t)(m0 + w * 16 + lg * 4 + r) * EE + n0 + ct * 16 + lr] = acc[ct][r];
}

__global__ __launch_bounds__(256) void zero_f32(float* __restrict__ p, int n4) {
    int i = blockIdx.x * 256 + threadIdx.x;
    if (i < n4) ((float4*)p)[i] = make_float4(0.f, 0.f, 0.f, 0.f);
}

// ---------------------------------------------------------------------------
// MFMA attention. Block = (h, frame-group, n); 4 waves; wave w owns queries
// [w*16, w*16+16). K in swizzled [208][64] LDS; scores in regs (col=q);
// register softmax; Pt/Vt (stride 232) -> PV; atomicAdd into mix.
// ---------------------------------------------------------------------------
__global__ __launch_bounds__(256, 2) void attn_mfma(const float* __restrict__ qs_g,
                                                    const float* __restrict__ k_g,
                                                    const float* __restrict__ v_g,
                                                    const int* __restrict__ m_g,
                                                    float* __restrict__ mix_g) {
    const int h = blockIdx.x, fg = blockIdx.y, n = blockIdx.z;

    __shared__ unsigned short KV_s[64 * VST];   // K view: [208][64] swizzled; Vt view: [64][232]
    __shared__ unsigned short Pt_s[64 * VST];   // P^T: [q=64][p<=224]
    __shared__ float bias_s[224];
    __shared__ float linv_s[4][16];

    const int t = threadIdx.x;
    const int w = t >> 6, lane = t & 63, lr = lane & 15, lg = lane >> 4;

    // zero Pt pad cols [208,224) once (PV reads them; never rewritten)
    {
        int qr = t >> 2, c0 = 208 + (t & 3) * 4;
        *(s16x4*)&Pt_s[qr * VST + c0] = (s16x4){0, 0, 0, 0};
    }
    // Q fragments straight to registers (scaled by d^-0.5)
    bf16x8 qb0, qb1;
    {
        const float* qp = qs_g + ((size_t)n * QN + w * 16 + lr) * EE + h * DH + lg * 8;
        f32x4 a = *(const f32x4*)qp, b = *(const f32x4*)(qp + 4);
        f32x4 c = *(const f32x4*)(qp + 32), d = *(const f32x4*)(qp + 36);
#pragma unroll
        for (int i = 0; i < 4; ++i) { a[i] *= 0.125f; b[i] *= 0.125f; c[i] *= 0.125f; d[i] *= 0.125f; }
        qb0 = cvt8(a, b);
        qb1 = cvt8(c, d);
    }

    float mix[4][4];
#pragma unroll
    for (int dt = 0; dt < 4; ++dt)
#pragma unroll
        for (int r = 0; r < 4; ++r) mix[dt][r] = 0.f;

    for (int ff = 0; ff < FPB; ++ff) {
        const int f = fg * FPB + ff;
        const size_t kbase = (size_t)n * KLEN + f * LP;

        __syncthreads();  // prev PV / bias readers done before overwrite

        // ---- stage K [208][64] bf16, XOR-swizzled 16B blocks ----
#pragma unroll
        for (int u = 0; u < 7; ++u) {
            int unit = t + 256 * u;
            if (unit < KROWS * 8) {
                int p = unit >> 3, blk = unit & 7;
                f32x4 a = {0.f, 0.f, 0.f, 0.f}, b = {0.f, 0.f, 0.f, 0.f};
                if (p < LP) {
                    const float* src = k_g + ((kbase + p) * HN + h) * DH + blk * 8;
                    a = *(const f32x4*)src;
                    b = *(const f32x4*)(src + 4);
                }
                *(bf16x8*)&KV_s[p * 64 + ((blk ^ (p & 7)) << 3)] = cvt8(a, b);
            }
        }
        if (t < 224) {
            float bv = -1e30f;
            if (t < LP && m_g[kbase + t] != 0) bv = 0.f;
            bias_s[t] = bv;
        }
        __syncthreads();

        // ---- QK^T: lane holds scores for q = w*16+lr, p = tl*16 + lg*4 + r ----
        f32x4 sc[13];
#pragma unroll
        for (int tl = 0; tl < 13; ++tl) {
            int row = tl * 16 + lr;
            bf16x8 a0 = *(const bf16x8*)&KV_s[row * 64 + ((lg ^ (lr & 7)) << 3)];
            bf16x8 a1 = *(const bf16x8*)&KV_s[row * 64 + (((4 + lg) ^ (lr & 7)) << 3)];
            f32x4 z = {0.f, 0.f, 0.f, 0.f};
            z = __builtin_amdgcn_mfma_f32_16x16x32_bf16(a0, qb0, z, 0, 0, 0);
            sc[tl] = __builtin_amdgcn_mfma_f32_16x16x32_bf16(a1, qb1, z, 0, 0, 0);
        }

        // ---- issue V loads early; unit = d4*112 + pp (conflict-free Vt writes) ----
        f32x4 va[7], vb[7];
#pragma unroll
        for (int u = 0; u < 7; ++u) {
            int unit = t + 256 * u;
            int d4 = unit / 112, pp = unit % 112;
            int p0 = pp * 2;
            va[u] = (f32x4){0.f, 0.f, 0.f, 0.f};
            vb[u] = (f32x4){0.f, 0.f, 0.f, 0.f};
            if (p0 < LP) {
                const float* vg = v_g + ((kbase + p0) * HN + h) * DH + d4 * 4;
                va[u] = *(const f32x4*)vg;
                if (p0 + 1 < LP) vb[u] = *(const f32x4*)(vg + (size_t)HN * DH);
            }
        }

        // ---- register softmax over 208 patches ----
        float mx = -FLT_MAX;
#pragma unroll
        for (int tl = 0; tl < 13; ++tl)
#pragma unroll
            for (int r = 0; r < 4; ++r) {
                float sv = sc[tl][r] + bias_s[tl * 16 + lg * 4 + r];
                sc[tl][r] = sv;
                mx = fmaxf(mx, sv);
            }
        mx = fmaxf(mx, __shfl_xor(mx, 16));
        mx = fmaxf(mx, __shfl_xor(mx, 32));
        float sum = 0.f;
#pragma unroll
        for (int tl = 0; tl < 13; ++tl)
#pragma unroll
            for (int r = 0; r < 4; ++r) {
                float e = __expf(sc[tl][r] - mx);
                sc[tl][r] = e;
                sum += e;
            }
        sum += __shfl_xor(sum, 16);
        sum += __shfl_xor(sum, 32);
        if (lane < 16) linv_s[w][lane] = 1.0f / sum;

        // ---- write P^T: row q = w*16+lr, cols p = tl*16 + lg*4 + {0..3} ----
#pragma unroll
        for (int tl = 0; tl < 13; ++tl) {
            s16x4 pb = {(short)bfb(sc[tl][0]), (short)bfb(sc[tl][1]),
                        (short)bfb(sc[tl][2]), (short)bfb(sc[tl][3])};
            *(s16x4*)&Pt_s[(w * 16 + lr) * VST + tl * 16 + lg * 4] = pb;
        }
        __syncthreads();  // all waves done reading K before Vt overwrites union

        // ---- write V^T: row d = d4*4+i, col pair p0 (pair-packed b32) ----
#pragma unroll
        for (int u = 0; u < 7; ++u) {
            int unit = t + 256 * u;
            int d4 = unit / 112, pp = unit % 112;
            int p0 = pp * 2;
#pragma unroll
            for (int i = 0; i < 4; ++i) {
                unsigned pk = (unsigned)bfb(va[u][i]) | ((unsigned)bfb(vb[u][i]) << 16);
                *(unsigned*)&KV_s[(d4 * 4 + i) * VST + p0] = pk;
            }
        }
        __syncthreads();

        // ---- PV: C2[q][d] = sum_p Pt[q][p] * Vt[d][p] ----
        f32x4 pv[4];
#pragma unroll
        for (int dt = 0; dt < 4; ++dt) pv[dt] = (f32x4){0.f, 0.f, 0.f, 0.f};
#pragma unroll
        for (int ks = 0; ks < 7; ++ks) {
            bf16x8 a = *(const bf16x8*)&Pt_s[(w * 16 + lr) * VST + ks * 32 + lg * 8];
#pragma unroll
            for (int dt = 0; dt < 4; ++dt) {
                bf16x8 b = *(const bf16x8*)&KV_s[(dt * 16 + lr) * VST + ks * 32 + lg * 8];
                pv[dt] = __builtin_amdgcn_mfma_f32_16x16x32_bf16(a, b, pv[dt], 0, 0, 0);
            }
        }
        float li[4];
#pragma unroll
        for (int r = 0; r < 4; ++r) li[r] = linv_s[w][lg * 4 + r];
#pragma unroll
        for (int dt = 0; dt < 4; ++dt)
#pragma unroll
            for (int r = 0; r < 4; ++r) mix[dt][r] += pv[dt][r] * li[r];
    }

    // ---- accumulate into mix[n][q = w*16 + lg*4 + r][h*64 + dt*16 + lr] ----
#pragma unroll
    for (int dt = 0; dt < 4; ++dt)
#pragma unroll
        for (int r = 0; r < 4; ++r)
            atomicAdd(mix_g + ((size_t)n * QN + w * 16 + lg * 4 + r) * EE + h * DH + dt * 16 + lr,
                      mix[dt][r]);
}

// ---------------------------------------------------------------------------
extern "C" void kernel_launch(void* const* d_in, const int* in_sizes, int n_in,
                              void* d_out, int out_size, void* d_ws, size_t ws_size,
                              hipStream_t stream) {
    const float* q  = (const float*)d_in[0];
    const float* k  = (const float*)d_in[1];
    const float* v  = (const float*)d_in[2];
    const int*   m  = (const int*)d_in[3];
    const float* Wi = (const float*)d_in[4];
    const float* Wo = (const float*)d_in[5];

    float* out = (float*)d_out;
    float* qs  = out + (size_t)N_B * QN * EE;  // second output (qs_out), also attn input
    float* mix = (float*)d_ws;                 // 2048x768 fp32 scratch (atomic-accumulated)

    const int mix_n4 = (N_B * QN * EE) / 4;
    dim3 ggrid((N_B * QN) / 64, EE / 48);
    gemm_mfma<<<ggrid, 256, 0, stream>>>(q, Wi, qs);                             // in-proj
    zero_f32<<<(mix_n4 + 255) / 256, 256, 0, stream>>>(mix, mix_n4);             // zero mix
    attn_mfma<<<dim3(HN, FN / FPB, N_B), 256, 0, stream>>>(qs, k, v, m, mix);    // attention
    gemm_mfma<<<ggrid, 256, 0, stream>>>(mix, Wo, out);                          // out-proj
}